// Round 1
// baseline (3186.065 us; speedup 1.0000x reference)
//
#include <hip/hip_runtime.h>

// Problem constants (match reference)
#define OUT_F 4096
#define IN_F  4096
#define NCOLS 8192

// Workspace layout (ints):
//   counts  : [0, 4097)
//   offsets : [4097, 8194)
//   cursor  : [8194, 12290)
//   cols_s  : [12290, 12290+nnz)
//   vals_s  : [12290+nnz, 12290+2*nnz)
#define WS_COUNTS  0
#define WS_OFFSETS 4097
#define WS_CURSOR  8194
#define WS_HEADER  12290

__global__ void hist_kernel(const int* __restrict__ rows, int* __restrict__ counts, int nnz) {
    int i = blockIdx.x * blockDim.x + threadIdx.x;
    if (i < nnz) atomicAdd(&counts[rows[i]], 1);
}

// Exclusive prefix sum over 4096 row counts. 256 threads x 16 elements each.
__global__ void scan_kernel(const int* __restrict__ counts, int* __restrict__ offsets) {
    __shared__ int lsum[256];
    int t = threadIdx.x;
    int base = t * 16;
    int local[16];
    int s = 0;
    for (int i = 0; i < 16; ++i) { local[i] = counts[base + i]; s += local[i]; }
    lsum[t] = s;
    __syncthreads();
    if (t == 0) {
        int acc = 0;
        for (int i = 0; i < 256; ++i) { int v = lsum[i]; lsum[i] = acc; acc += v; }
        offsets[OUT_F] = acc;  // total nnz
    }
    __syncthreads();
    int acc = lsum[t];
    for (int i = 0; i < 16; ++i) { offsets[base + i] = acc; acc += local[i]; }
}

__global__ void scatter_kernel(const int* __restrict__ rows, const int* __restrict__ cols,
                               const float* __restrict__ vals,
                               const int* __restrict__ offsets, int* __restrict__ cursor,
                               int* __restrict__ cols_s, float* __restrict__ vals_s, int nnz) {
    int i = blockIdx.x * blockDim.x + threadIdx.x;
    if (i < nnz) {
        int r = rows[i];
        int pos = offsets[r] + atomicAdd(&cursor[r], 1);
        cols_s[pos] = cols[i];
        vals_s[pos] = vals[i];
    }
}

// One block per (row, 1024-column tile). 256 threads, float4 per thread.
__global__ __launch_bounds__(256) void spmm_kernel(const int* __restrict__ offsets,
                                                   const int* __restrict__ cols_s,
                                                   const float* __restrict__ vals_s,
                                                   const float* __restrict__ x,
                                                   float* __restrict__ out) {
    const int row  = blockIdx.x;
    const int col0 = blockIdx.y * 1024 + threadIdx.x * 4;
    const int k0 = offsets[row];
    const int k1 = offsets[row + 1];
    float4 acc = make_float4(0.f, 0.f, 0.f, 0.f);
    for (int k = k0; k < k1; ++k) {
        const int   c = cols_s[k];
        const float v = vals_s[k];
        const float4 xv = *reinterpret_cast<const float4*>(x + (size_t)c * NCOLS + col0);
        acc.x += v * xv.x;
        acc.y += v * xv.y;
        acc.z += v * xv.z;
        acc.w += v * xv.w;
    }
    *reinterpret_cast<float4*>(out + (size_t)row * NCOLS + col0) = acc;
}

extern "C" void kernel_launch(void* const* d_in, const int* in_sizes, int n_in,
                              void* d_out, int out_size, void* d_ws, size_t ws_size,
                              hipStream_t stream) {
    const int*   rows = (const int*)d_in[0];
    const int*   cols = (const int*)d_in[1];
    const float* vals = (const float*)d_in[2];
    const float* x    = (const float*)d_in[3];
    float*       out  = (float*)d_out;

    const int nnz = in_sizes[0];

    int*   ws_i    = (int*)d_ws;
    int*   counts  = ws_i + WS_COUNTS;
    int*   offsets = ws_i + WS_OFFSETS;
    int*   cursor  = ws_i + WS_CURSOR;
    int*   cols_s  = ws_i + WS_HEADER;
    float* vals_s  = (float*)(ws_i + WS_HEADER + nnz);

    // Zero counts/cursor (offsets overwritten by scan). Workspace is re-poisoned
    // to 0xAA before every timed call, so this must happen every launch.
    hipMemsetAsync(d_ws, 0, (size_t)WS_HEADER * sizeof(int), stream);

    const int threads = 256;
    const int nblk = (nnz + threads - 1) / threads;

    hist_kernel<<<nblk, threads, 0, stream>>>(rows, counts, nnz);
    scan_kernel<<<1, 256, 0, stream>>>(counts, offsets);
    scatter_kernel<<<nblk, threads, 0, stream>>>(rows, cols, vals, offsets, cursor,
                                                 cols_s, vals_s, nnz);

    dim3 grid(OUT_F, NCOLS / 1024);
    spmm_kernel<<<grid, threads, 0, stream>>>(offsets, cols_s, vals_s, x, out);
}

// Round 2
// 673.467 us; speedup vs baseline: 4.7308x; 4.7308x over previous
//
#include <hip/hip_runtime.h>

// Problem constants (match reference)
#define OUT_F 4096   // M
#define IN_F  4096   // K
#define NCOLS 8192   // N

#define GM OUT_F
#define GK IN_F
#define GN NCOLS

typedef __attribute__((ext_vector_type(8))) short short8;
typedef __attribute__((ext_vector_type(4))) float f32x4;

// ---------------------------------------------------------------------------
// helpers
// ---------------------------------------------------------------------------
__device__ inline unsigned short f2bf(float f) {
    union { float f; unsigned u; } c; c.f = f;
    unsigned u = c.u;
    u += 0x7fffu + ((u >> 16) & 1u);   // round-to-nearest-even
    return (unsigned short)(u >> 16);
}

__device__ inline void gll16(const void* g, void* l) {
    __builtin_amdgcn_global_load_lds(
        (const __attribute__((address_space(1))) unsigned int*)g,
        (__attribute__((address_space(3))) unsigned int*)l, 16, 0, 0);
}

// ---------------------------------------------------------------------------
// Densify path
// ---------------------------------------------------------------------------
__global__ void scatter_dense(const int* __restrict__ rows, const int* __restrict__ cols,
                              const float* __restrict__ vals, float* __restrict__ W, int nnz) {
    int i = blockIdx.x * blockDim.x + threadIdx.x;
    if (i < nnz) atomicAdd(&W[(size_t)rows[i] * IN_F + cols[i]], vals[i]);
}

__global__ void convert_w(const float* __restrict__ Wf, unsigned short* __restrict__ Wb) {
    int i = blockIdx.x * blockDim.x + threadIdx.x;  // over elems/4
    float4 v = ((const float4*)Wf)[i];
    ushort4 o;
    o.x = f2bf(v.x); o.y = f2bf(v.y); o.z = f2bf(v.z); o.w = f2bf(v.w);
    ((ushort4*)Wb)[i] = o;
}

// x [IN_F][NCOLS] f32 -> xT [NCOLS][IN_F] bf16, 64x64 tiles via LDS
__global__ __launch_bounds__(256) void transpose_x(const float* __restrict__ x,
                                                   unsigned short* __restrict__ xT) {
    __shared__ float tile[64][65];
    const int k0 = blockIdx.x * 64;   // x row block (K dim)
    const int n0 = blockIdx.y * 64;   // x col block (N dim)
    const int t = threadIdx.x;
    const int c4 = (t & 15) * 4;
    const int r0 = t >> 4;            // 0..15
    for (int p = 0; p < 4; ++p) {
        int r = r0 + p * 16;
        float4 v = *(const float4*)&x[(size_t)(k0 + r) * NCOLS + n0 + c4];
        tile[r][c4 + 0] = v.x; tile[r][c4 + 1] = v.y;
        tile[r][c4 + 2] = v.z; tile[r][c4 + 3] = v.w;
    }
    __syncthreads();
    const int n  = t >> 2;            // 0..63
    const int ks = (t & 3) * 16;      // 0,16,32,48
    unsigned w[8];
    for (int m = 0; m < 8; ++m) {
        unsigned short lo = f2bf(tile[ks + 2 * m + 0][n]);
        unsigned short hi = f2bf(tile[ks + 2 * m + 1][n]);
        w[m] = (unsigned)lo | ((unsigned)hi << 16);
    }
    uint4* dst = (uint4*)&xT[(size_t)(n0 + n) * GK + k0 + ks];
    dst[0] = make_uint4(w[0], w[1], w[2], w[3]);
    dst[1] = make_uint4(w[4], w[5], w[6], w[7]);
}

// ---------------------------------------------------------------------------
// GEMM: C[GM][GN] f32 = A(bf16 [GM][GK]) * B, with B given as BT bf16 [GN][GK].
// m97 structure: 128x128 tile, 256 thr (4 waves, 2x2), 4x4 16x16x32 MFMA/wave,
// BK=64, global_load_lds width 16.
// ---------------------------------------------------------------------------
__global__ __launch_bounds__(256) void gemm_bt(const unsigned short* __restrict__ A,
                                               const unsigned short* __restrict__ BT,
                                               float* __restrict__ C) {
    __shared__ unsigned short As[128 * 64];
    __shared__ unsigned short Bs[128 * 64];

    const int tid  = threadIdx.x;
    const int wave = tid >> 6;
    const int lane = tid & 63;
    const int m0 = blockIdx.y * 128;
    const int n0 = blockIdx.x * 128;
    const int wm = (wave >> 1) * 64;   // wave M offset in tile
    const int wn = (wave & 1) * 64;    // wave N offset in tile
    // staging lane mapping: issue covers 8 rows x 64 k; lane i -> row i/8, k (i%8)*8
    const int lrow = lane >> 3;
    const int lk   = (lane & 7) * 8;
    // fragment lane mapping for 16x16x32: outer = lane&15, k = (lane>>4)*8
    const int frow = lane & 15;
    const int fk   = (lane >> 4) * 8;

    f32x4 acc[4][4] = {};

    const unsigned short* aBase = A  + (size_t)(m0 + wave * 32 + lrow) * GK + lk;
    const unsigned short* bBase = BT + (size_t)(n0 + wave * 32 + lrow) * GK + lk;

    for (int kt = 0; kt < GK / 64; ++kt) {
        const int k0 = kt * 64;
        for (int j = 0; j < 4; ++j) {
            gll16(aBase + (size_t)j * 8 * GK + k0, &As[(wave * 4 + j) * 512]);
            gll16(bBase + (size_t)j * 8 * GK + k0, &Bs[(wave * 4 + j) * 512]);
        }
        __syncthreads();   // drains vmcnt before LDS reads
        for (int s = 0; s < 2; ++s) {
            const int kk = s * 32 + fk;
            short8 af[4], bq[4];
            for (int i = 0; i < 4; ++i)
                af[i] = *(const short8*)&As[(wm + i * 16 + frow) * 64 + kk];
            for (int j = 0; j < 4; ++j)
                bq[j] = *(const short8*)&Bs[(wn + j * 16 + frow) * 64 + kk];
            for (int i = 0; i < 4; ++i)
                for (int j = 0; j < 4; ++j)
                    acc[i][j] = __builtin_amdgcn_mfma_f32_16x16x32_bf16(
                        af[i], bq[j], acc[i][j], 0, 0, 0);
        }
        __syncthreads();
    }

    // epilogue: C/D layout col=lane&15, row=(lane>>4)*4+reg
    for (int i = 0; i < 4; ++i) {
        const int r0 = m0 + wm + i * 16 + (lane >> 4) * 4;
        for (int j = 0; j < 4; ++j) {
            const int cc = n0 + wn + j * 16 + frow;
            for (int r = 0; r < 4; ++r)
                C[(size_t)(r0 + r) * GN + cc] = acc[i][j][r];
        }
    }
}

// ---------------------------------------------------------------------------
// Fallback SpMM path (round-1 kernel) if workspace is too small for densify
// ---------------------------------------------------------------------------
#define WS_COUNTS  0
#define WS_OFFSETS 4097
#define WS_CURSOR  8194
#define WS_HEADER  12290

__global__ void hist_kernel(const int* __restrict__ rows, int* __restrict__ counts, int nnz) {
    int i = blockIdx.x * blockDim.x + threadIdx.x;
    if (i < nnz) atomicAdd(&counts[rows[i]], 1);
}

__global__ void scan_kernel(const int* __restrict__ counts, int* __restrict__ offsets) {
    __shared__ int lsum[256];
    int t = threadIdx.x;
    int base = t * 16;
    int local[16];
    int s = 0;
    for (int i = 0; i < 16; ++i) { local[i] = counts[base + i]; s += local[i]; }
    lsum[t] = s;
    __syncthreads();
    if (t == 0) {
        int acc = 0;
        for (int i = 0; i < 256; ++i) { int v = lsum[i]; lsum[i] = acc; acc += v; }
        offsets[OUT_F] = acc;
    }
    __syncthreads();
    int acc = lsum[t];
    for (int i = 0; i < 16; ++i) { offsets[base + i] = acc; acc += local[i]; }
}

__global__ void scatter_kernel(const int* __restrict__ rows, const int* __restrict__ cols,
                               const float* __restrict__ vals,
                               const int* __restrict__ offsets, int* __restrict__ cursor,
                               int* __restrict__ cols_s, float* __restrict__ vals_s, int nnz) {
    int i = blockIdx.x * blockDim.x + threadIdx.x;
    if (i < nnz) {
        int r = rows[i];
        int pos = offsets[r] + atomicAdd(&cursor[r], 1);
        cols_s[pos] = cols[i];
        vals_s[pos] = vals[i];
    }
}

__global__ __launch_bounds__(256) void spmm_kernel(const int* __restrict__ offsets,
                                                   const int* __restrict__ cols_s,
                                                   const float* __restrict__ vals_s,
                                                   const float* __restrict__ x,
                                                   float* __restrict__ out) {
    const int row  = blockIdx.x;
    const int col0 = blockIdx.y * 1024 + threadIdx.x * 4;
    const int k0 = offsets[row];
    const int k1 = offsets[row + 1];
    float4 acc = make_float4(0.f, 0.f, 0.f, 0.f);
    for (int k = k0; k < k1; ++k) {
        const int   c = cols_s[k];
        const float v = vals_s[k];
        const float4 xv = *reinterpret_cast<const float4*>(x + (size_t)c * NCOLS + col0);
        acc.x += v * xv.x;
        acc.y += v * xv.y;
        acc.z += v * xv.z;
        acc.w += v * xv.w;
    }
    *reinterpret_cast<float4*>(out + (size_t)row * NCOLS + col0) = acc;
}

// ---------------------------------------------------------------------------
extern "C" void kernel_launch(void* const* d_in, const int* in_sizes, int n_in,
                              void* d_out, int out_size, void* d_ws, size_t ws_size,
                              hipStream_t stream) {
    const int*   rows = (const int*)d_in[0];
    const int*   cols = (const int*)d_in[1];
    const float* vals = (const float*)d_in[2];
    const float* x    = (const float*)d_in[3];
    float*       out  = (float*)d_out;
    const int nnz = in_sizes[0];

    const size_t WF_BYTES = (size_t)GM * GK * 4;   // 64 MB fp32 W (later reused for xT)
    const size_t WB_BYTES = (size_t)GM * GK * 2;   // 32 MB bf16 W
    const size_t NEED = WF_BYTES + WB_BYTES;       // 96 MB

    if (ws_size >= NEED) {
        float*          Wf = (float*)d_ws;
        unsigned short* Wb = (unsigned short*)((char*)d_ws + WF_BYTES);
        unsigned short* xT = (unsigned short*)d_ws;  // reuses Wf region after convert_w

        hipMemsetAsync(Wf, 0, WF_BYTES, stream);
        scatter_dense<<<(nnz + 255) / 256, 256, 0, stream>>>(rows, cols, vals, Wf, nnz);
        convert_w<<<(GM * GK / 4) / 256, 256, 0, stream>>>(Wf, Wb);
        // Wf is dead now; overwrite its region with xT
        dim3 tg(GK / 64, GN / 64);
        transpose_x<<<tg, 256, 0, stream>>>(x, xT);
        dim3 gg(GN / 128, GM / 128);
        gemm_bt<<<gg, 256, 0, stream>>>(Wb, xT, out);
    } else {
        // fallback: CSR SpMM (round-1 path)
        int*   ws_i    = (int*)d_ws;
        int*   counts  = ws_i + WS_COUNTS;
        int*   offsets = ws_i + WS_OFFSETS;
        int*   cursor  = ws_i + WS_CURSOR;
        int*   cols_s  = ws_i + WS_HEADER;
        float* vals_s  = (float*)(ws_i + WS_HEADER + nnz);

        hipMemsetAsync(d_ws, 0, (size_t)WS_HEADER * sizeof(int), stream);
        const int nblk = (nnz + 255) / 256;
        hist_kernel<<<nblk, 256, 0, stream>>>(rows, counts, nnz);
        scan_kernel<<<1, 256, 0, stream>>>(counts, offsets);
        scatter_kernel<<<nblk, 256, 0, stream>>>(rows, cols, vals, offsets, cursor,
                                                 cols_s, vals_s, nnz);
        dim3 grid(OUT_F, NCOLS / 1024);
        spmm_kernel<<<grid, 256, 0, stream>>>(offsets, cols_s, vals_s, x, out);
    }
}

// Round 3
// 563.239 us; speedup vs baseline: 5.6567x; 1.1957x over previous
//
#include <hip/hip_runtime.h>

// Problem constants (match reference)
#define OUT_F 4096   // M
#define IN_F  4096   // K
#define NCOLS 8192   // N

#define GM OUT_F
#define GK IN_F
#define GN NCOLS

typedef __attribute__((ext_vector_type(8))) short short8;
typedef __attribute__((ext_vector_type(4))) float f32x4;

// ---------------------------------------------------------------------------
// helpers
// ---------------------------------------------------------------------------
__device__ inline unsigned short f2bf(float f) {
    union { float f; unsigned u; } c; c.f = f;
    unsigned u = c.u;
    u += 0x7fffu + ((u >> 16) & 1u);   // round-to-nearest-even
    return (unsigned short)(u >> 16);
}

__device__ inline void gll16(const void* g, void* l) {
    __builtin_amdgcn_global_load_lds(
        (const __attribute__((address_space(1))) unsigned int*)g,
        (__attribute__((address_space(3))) unsigned int*)l, 16, 0, 0);
}

// ---------------------------------------------------------------------------
// Densify path
// ---------------------------------------------------------------------------
__global__ void scatter_dense(const int* __restrict__ rows, const int* __restrict__ cols,
                              const float* __restrict__ vals, float* __restrict__ W, int nnz) {
    int i = blockIdx.x * blockDim.x + threadIdx.x;
    if (i < nnz) atomicAdd(&W[(size_t)rows[i] * IN_F + cols[i]], vals[i]);
}

__global__ void convert_w(const float* __restrict__ Wf, unsigned short* __restrict__ Wb) {
    int i = blockIdx.x * blockDim.x + threadIdx.x;  // over elems/4
    float4 v = ((const float4*)Wf)[i];
    ushort4 o;
    o.x = f2bf(v.x); o.y = f2bf(v.y); o.z = f2bf(v.z); o.w = f2bf(v.w);
    ((ushort4*)Wb)[i] = o;
}

// x [IN_F][NCOLS] f32 -> xT [NCOLS][IN_F] bf16, 64x64 tiles via LDS
__global__ __launch_bounds__(256) void transpose_x(const float* __restrict__ x,
                                                   unsigned short* __restrict__ xT) {
    __shared__ float tile[64][65];
    const int k0 = blockIdx.x * 64;   // x row block (K dim)
    const int n0 = blockIdx.y * 64;   // x col block (N dim)
    const int t = threadIdx.x;
    const int c4 = (t & 15) * 4;
    const int r0 = t >> 4;            // 0..15
    for (int p = 0; p < 4; ++p) {
        int r = r0 + p * 16;
        float4 v = *(const float4*)&x[(size_t)(k0 + r) * NCOLS + n0 + c4];
        tile[r][c4 + 0] = v.x; tile[r][c4 + 1] = v.y;
        tile[r][c4 + 2] = v.z; tile[r][c4 + 3] = v.w;
    }
    __syncthreads();
    const int n  = t >> 2;            // 0..63
    const int ks = (t & 3) * 16;      // 0,16,32,48
    unsigned w[8];
    for (int m = 0; m < 8; ++m) {
        unsigned short lo = f2bf(tile[ks + 2 * m + 0][n]);
        unsigned short hi = f2bf(tile[ks + 2 * m + 1][n]);
        w[m] = (unsigned)lo | ((unsigned)hi << 16);
    }
    uint4* dst = (uint4*)&xT[(size_t)(n0 + n) * GK + k0 + ks];
    dst[0] = make_uint4(w[0], w[1], w[2], w[3]);
    dst[1] = make_uint4(w[4], w[5], w[6], w[7]);
}

// ---------------------------------------------------------------------------
// GEMM: C[GM][GN] f32 = A(bf16 [GM][GK]) * B, with B given as BT bf16 [GN][GK].
// m97 structure: 128x128 tile, 256 thr (4 waves, 2x2), 4x4 16x16x32 MFMA/wave,
// BK=64, global_load_lds width 16.
// LDS XOR swizzle: 16B k-block j of row r is stored at block slot j^(r&7).
// Staging picks the permuted global block per lane (same 128B segment ->
// coalescing preserved); fragment reads spread across all 32 banks (2-way
// aliasing only, which is free).
// ---------------------------------------------------------------------------
__global__ __launch_bounds__(256) void gemm_bt(const unsigned short* __restrict__ A,
                                               const unsigned short* __restrict__ BT,
                                               float* __restrict__ C) {
    __shared__ unsigned short As[128 * 64];
    __shared__ unsigned short Bs[128 * 64];

    const int tid  = threadIdx.x;
    const int wave = tid >> 6;
    const int lane = tid & 63;
    const int m0 = blockIdx.y * 128;
    const int n0 = blockIdx.x * 128;
    const int wm = (wave >> 1) * 64;   // wave M offset in tile
    const int wn = (wave & 1) * 64;    // wave N offset in tile
    // staging lane mapping: issue covers 8 rows x 64 k; lane i -> row i/8.
    // XOR swizzle: lane i fetches global k-block (i&7)^(lrow&7) so that the
    // fixed LDS slot (i&7) holds swizzled data.
    const int lrow = lane >> 3;
    const int lk   = ((lane & 7) ^ (lrow & 7)) * 8;
    // fragment lane mapping for 16x16x32: outer = lane&15, k-block j = s*4+(lane>>4)
    const int frow = lane & 15;
    const int jhi  = lane >> 4;        // 0..3

    f32x4 acc[4][4] = {};

    const unsigned short* aBase = A  + (size_t)(m0 + wave * 32 + lrow) * GK + lk;
    const unsigned short* bBase = BT + (size_t)(n0 + wave * 32 + lrow) * GK + lk;

    for (int kt = 0; kt < GK / 64; ++kt) {
        const int k0 = kt * 64;
        for (int j = 0; j < 4; ++j) {
            gll16(aBase + (size_t)j * 8 * GK + k0, &As[(wave * 4 + j) * 512]);
            gll16(bBase + (size_t)j * 8 * GK + k0, &Bs[(wave * 4 + j) * 512]);
        }
        __syncthreads();   // drains vmcnt before LDS reads
        for (int s = 0; s < 2; ++s) {
            const int jblk = s * 4 + jhi;                    // k-block 0..7
            const int kswz = (jblk ^ (frow & 7)) * 8;        // swizzled elem offset
            short8 af[4], bq[4];
            for (int i = 0; i < 4; ++i)
                af[i] = *(const short8*)&As[(wm + i * 16 + frow) * 64 + kswz];
            for (int j = 0; j < 4; ++j)
                bq[j] = *(const short8*)&Bs[(wn + j * 16 + frow) * 64 + kswz];
            for (int i = 0; i < 4; ++i)
                for (int j = 0; j < 4; ++j)
                    acc[i][j] = __builtin_amdgcn_mfma_f32_16x16x32_bf16(
                        af[i], bq[j], acc[i][j], 0, 0, 0);
        }
        __syncthreads();
    }

    // epilogue: C/D layout col=lane&15, row=(lane>>4)*4+reg
    for (int i = 0; i < 4; ++i) {
        const int r0 = m0 + wm + i * 16 + (lane >> 4) * 4;
        for (int j = 0; j < 4; ++j) {
            const int cc = n0 + wn + j * 16 + frow;
            for (int r = 0; r < 4; ++r)
                C[(size_t)(r0 + r) * GN + cc] = acc[i][j][r];
        }
    }
}

// ---------------------------------------------------------------------------
// Fallback SpMM path (round-1 kernel) if workspace is too small for densify
// ---------------------------------------------------------------------------
#define WS_COUNTS  0
#define WS_OFFSETS 4097
#define WS_CURSOR  8194
#define WS_HEADER  12290

__global__ void hist_kernel(const int* __restrict__ rows, int* __restrict__ counts, int nnz) {
    int i = blockIdx.x * blockDim.x + threadIdx.x;
    if (i < nnz) atomicAdd(&counts[rows[i]], 1);
}

__global__ void scan_kernel(const int* __restrict__ counts, int* __restrict__ offsets) {
    __shared__ int lsum[256];
    int t = threadIdx.x;
    int base = t * 16;
    int local[16];
    int s = 0;
    for (int i = 0; i < 16; ++i) { local[i] = counts[base + i]; s += local[i]; }
    lsum[t] = s;
    __syncthreads();
    if (t == 0) {
        int acc = 0;
        for (int i = 0; i < 256; ++i) { int v = lsum[i]; lsum[i] = acc; acc += v; }
        offsets[OUT_F] = acc;
    }
    __syncthreads();
    int acc = lsum[t];
    for (int i = 0; i < 16; ++i) { offsets[base + i] = acc; acc += local[i]; }
}

__global__ void scatter_kernel(const int* __restrict__ rows, const int* __restrict__ cols,
                               const float* __restrict__ vals,
                               const int* __restrict__ offsets, int* __restrict__ cursor,
                               int* __restrict__ cols_s, float* __restrict__ vals_s, int nnz) {
    int i = blockIdx.x * blockDim.x + threadIdx.x;
    if (i < nnz) {
        int r = rows[i];
        int pos = offsets[r] + atomicAdd(&cursor[r], 1);
        cols_s[pos] = cols[i];
        vals_s[pos] = vals[i];
    }
}

__global__ __launch_bounds__(256) void spmm_kernel(const int* __restrict__ offsets,
                                                   const int* __restrict__ cols_s,
                                                   const float* __restrict__ vals_s,
                                                   const float* __restrict__ x,
                                                   float* __restrict__ out) {
    const int row  = blockIdx.x;
    const int col0 = blockIdx.y * 1024 + threadIdx.x * 4;
    const int k0 = offsets[row];
    const int k1 = offsets[row + 1];
    float4 acc = make_float4(0.f, 0.f, 0.f, 0.f);
    for (int k = k0; k < k1; ++k) {
        const int   c = cols_s[k];
        const float v = vals_s[k];
        const float4 xv = *reinterpret_cast<const float4*>(x + (size_t)c * NCOLS + col0);
        acc.x += v * xv.x;
        acc.y += v * xv.y;
        acc.z += v * xv.z;
        acc.w += v * xv.w;
    }
    *reinterpret_cast<float4*>(out + (size_t)row * NCOLS + col0) = acc;
}

// ---------------------------------------------------------------------------
extern "C" void kernel_launch(void* const* d_in, const int* in_sizes, int n_in,
                              void* d_out, int out_size, void* d_ws, size_t ws_size,
                              hipStream_t stream) {
    const int*   rows = (const int*)d_in[0];
    const int*   cols = (const int*)d_in[1];
    const float* vals = (const float*)d_in[2];
    const float* x    = (const float*)d_in[3];
    float*       out  = (float*)d_out;
    const int nnz = in_sizes[0];

    const size_t WF_BYTES = (size_t)GM * GK * 4;   // 64 MB fp32 W (later reused for xT)
    const size_t WB_BYTES = (size_t)GM * GK * 2;   // 32 MB bf16 W
    const size_t NEED = WF_BYTES + WB_BYTES;       // 96 MB

    if (ws_size >= NEED) {
        float*          Wf = (float*)d_ws;
        unsigned short* Wb = (unsigned short*)((char*)d_ws + WF_BYTES);
        unsigned short* xT = (unsigned short*)d_ws;  // reuses Wf region after convert_w

        hipMemsetAsync(Wf, 0, WF_BYTES, stream);
        scatter_dense<<<(nnz + 255) / 256, 256, 0, stream>>>(rows, cols, vals, Wf, nnz);
        convert_w<<<(GM * GK / 4) / 256, 256, 0, stream>>>(Wf, Wb);
        // Wf is dead now; overwrite its region with xT
        dim3 tg(GK / 64, GN / 64);
        transpose_x<<<tg, 256, 0, stream>>>(x, xT);
        dim3 gg(GN / 128, GM / 128);
        gemm_bt<<<gg, 256, 0, stream>>>(Wb, xT, out);
    } else {
        // fallback: CSR SpMM (round-1 path)
        int*   ws_i    = (int*)d_ws;
        int*   counts  = ws_i + WS_COUNTS;
        int*   offsets = ws_i + WS_OFFSETS;
        int*   cursor  = ws_i + WS_CURSOR;
        int*   cols_s  = ws_i + WS_HEADER;
        float* vals_s  = (float*)(ws_i + WS_HEADER + nnz);

        hipMemsetAsync(d_ws, 0, (size_t)WS_HEADER * sizeof(int), stream);
        const int nblk = (nnz + 255) / 256;
        hist_kernel<<<nblk, 256, 0, stream>>>(rows, counts, nnz);
        scan_kernel<<<1, 256, 0, stream>>>(counts, offsets);
        scatter_kernel<<<nblk, 256, 0, stream>>>(rows, cols, vals, offsets, cursor,
                                                 cols_s, vals_s, nnz);
        dim3 grid(OUT_F, NCOLS / 1024);
        spmm_kernel<<<grid, 256, 0, stream>>>(offsets, cols_s, vals_s, x, out);
    }
}